// Round 1
// baseline (272.759 us; speedup 1.0000x reference)
//
#include <hip/hip_runtime.h>
#include <math.h>

typedef _Float16 half_t;
typedef __attribute__((ext_vector_type(8))) _Float16 half8;
typedef __attribute__((ext_vector_type(4))) _Float16 half4;
typedef __attribute__((ext_vector_type(4))) float floatx4;

#define TDIM 36
#define PDIM 161        // 2*80+1 atoms
#define NCOL 50
#define NITER 100
#define PITER2 200      // power steps on G^2 == 400 on G (proven R3/R4 accuracy)

// GEMM geometry: phase A K = p padded to 192 (6 ks of 32); phase B K = t padded to 64.
#define NKA 6
#define NKB 2
#define YKS 200         // Y row stride (halves): 100 dw, bank-balanced (verified R4 math)
#define RKS 72          // R / Dt row stride (halves): 36 dw
#define SPS 196         // Df (fp32) row stride

// ---- byte-offset LDS map (single fp16 iterate arrays; D keeps hi/lo) ----
#define BY_Y    0                      // [64][YKS] half : y^T      (25,600 B)
#define BY_R    25600                  // [64][RKS] half : R^T      ( 9,216 B)
#define BY_DTH  34816                  // [176][RKS] half: D^T hi   (25,344 B)
#define BY_DTL  60160                  // [176][RKS] half: D^T lo   (25,344 B)
#define BY_SC   85504                  // 2 floats: L_inv, thr
#define BY_GS   85520                  // [36][44] fp32 Gram        ( 6,336 B)
#define BY_G2   91856                  // [36][44] fp32 Gram^2      ( 6,336 B)
#define LDS_TOTAL 98192
// setup-only alias: Df [36][SPS] fp32 = 28,224 B over Y+R region (re-zeroed before loop)
#define GSTR 44

__global__ __launch_bounds__(512)
void dan_kernel(const float* __restrict__ xin, const float* __restrict__ rho,
                const float* __restrict__ theta, float* __restrict__ outC,
                float* __restrict__ outDic, float* __restrict__ outR)
{
  extern __shared__ char smc[];
  half_t* Yv  = (half_t*)(smc + BY_Y);
  half_t* Rv  = (half_t*)(smc + BY_R);
  half_t* Dth = (half_t*)(smc + BY_DTH);
  half_t* Dtl = (half_t*)(smc + BY_DTL);
  float*  sc  = (float*)(smc + BY_SC);
  float*  Gs  = (float*)(smc + BY_GS);
  float*  G2  = (float*)(smc + BY_G2);
  float*  Df  = (float*)(smc + BY_Y);   // setup alias over Y+R

  const int tid = threadIdx.x;
  const int b = blockIdx.x;
  const int wave = tid >> 6, lane = tid & 63;
  const int q = lane >> 4, ln = lane & 15;

  // ---- A. zero all LDS (pads must be 0)
  {
    unsigned int* z = (unsigned int*)smc;
    for (int i = tid; i < LDS_TOTAL / 4; i += 512) z[i] = 0u;
  }
  __syncthreads();

  // ---- B. build normalized dictionary (fp32, one column per thread)
  if (tid < PDIM) {
    if (tid == 0) {
      for (int t = 0; t < TDIM; ++t) Df[t * SPS] = 1.0f;
    } else {
      const bool is_sin = tid > 80;
      const int n = is_sin ? (tid - 81) : (tid - 1);
      const float rr = 0.001f + 1.149f / (1.0f + expf(-rho[n]));
      const float th = 3.14159265358979f / (1.0f + expf(-theta[n]));
      const float lr = logf(rr);
      float s2 = 0.0f;
      for (int t = 0; t < TDIM; ++t) {
        const float ft = (float)t;
        const float val = expf(ft * lr) * (is_sin ? sinf(ft * th) : cosf(ft * th));
        Df[t * SPS + tid] = val;
        s2 += val * val;
      }
      const float inv = 1.0f / sqrtf(s2);
      for (int t = 0; t < TDIM; ++t) Df[t * SPS + tid] *= inv;
    }
  }
  __syncthreads();

  // ---- C. Gram (upper tri + mirror) ; stage D^T hi/lo ; dic out
  for (int job = tid; job < 666; job += 512) {         // 666 = 36*37/2
    int i = 0, rem = job;
    while (rem >= TDIM - i) { rem -= TDIM - i; ++i; }
    const int j = i + rem;
    const float4* ri = (const float4*)(Df + i * SPS);
    const float4* rj = (const float4*)(Df + j * SPS);
    float a = 0.0f;
    #pragma unroll 7
    for (int k = 0; k < SPS / 4; ++k) {
      const float4 x = ri[k], y = rj[k];
      a += x.x * y.x + x.y * y.y + x.z * y.z + x.w * y.w;
    }
    Gs[i * GSTR + j] = a;
    Gs[j * GSTR + i] = a;
  }
  for (int i = tid; i < TDIM * PDIM; i += 512) {
    const int t = i / PDIM, p = i - t * PDIM;
    const float v = Df[t * SPS + p];
    const half_t h = (half_t)v;
    Dth[p * RKS + t] = h;
    Dtl[p * RKS + t] = (half_t)(v - (float)h);
    if (b == 0) outDic[i] = v;
  }
  __syncthreads();

  // ---- C2. G2 = G*G (cols 36..43 of Gs are zero)
  for (int job = tid; job < 666; job += 512) {
    int i = 0, rem = job;
    while (rem >= TDIM - i) { rem -= TDIM - i; ++i; }
    const int j = i + rem;
    const float4* ri = (const float4*)(Gs + i * GSTR);
    const float4* rj = (const float4*)(Gs + j * GSTR);
    float a = 0.0f;
    #pragma unroll
    for (int k = 0; k < GSTR / 4; ++k) {
      const float4 x = ri[k], y = rj[k];
      a += x.x * y.x + x.y * y.y + x.z * y.z + x.w * y.w;
    }
    G2[i * GSTR + j] = a;
    G2[j * GSTR + i] = a;
  }
  __syncthreads();

  // ---- D. ownership (R4 maps)
  const int mtA = wave >> 1;                 // phase A: waves 0..5
  const int ntA = (wave & 1) * 2;
  const int gB = wave >> 1;                  // phase B: all 8 waves
  const int nTB = (gB == 3) ? 2 : 3;
  const int nB0 = 32 * (wave & 1) + ln;

  // phase-A A-fragments (D hi/lo) from fp32 Df; rows >= 36 are zero
  half8 DhF[NKA], DlF[NKA];
  if (wave < 6) {
    const int row = 16 * mtA + ln;
    #pragma unroll
    for (int ks = 0; ks < NKA; ++ks) {
      half8 hh = {0,0,0,0,0,0,0,0}, ll = {0,0,0,0,0,0,0,0};
      if (row < TDIM) {
        const float4 f0 = *(const float4*)(Df + row * SPS + 32 * ks + 8 * q);
        const float4 f1 = *(const float4*)(Df + row * SPS + 32 * ks + 8 * q + 4);
        const float fa[8] = {f0.x, f0.y, f0.z, f0.w, f1.x, f1.y, f1.z, f1.w};
        #pragma unroll
        for (int e = 0; e < 8; ++e) {
          const half_t h = (half_t)fa[e];
          hh[e] = h;
          ll[e] = (half_t)(fa[e] - (float)h);
        }
      }
      DhF[ks] = hh;
      DlF[ks] = ll;
    }
  }
  // phase-B A-fragments (D^T hi/lo) from staged fp16
  half8 DtHF[3][NKB], DtLF[3][NKB];
  #pragma unroll
  for (int ti = 0; ti < 3; ++ti) {
    if (ti < nTB) {
      const int row = 16 * (gB + 4 * ti) + ln;
      #pragma unroll
      for (int ks = 0; ks < NKB; ++ks) {
        DtHF[ti][ks] = *(const half8*)(Dth + row * RKS + 32 * ks + 8 * q);
        DtLF[ti][ks] = *(const half8*)(Dtl + row * RKS + 32 * ks + 8 * q);
      }
    }
  }
  // static Y (fp32) at phase-A C positions
  float yA[2][4];
  if (wave < 6) {
    const float* xb = xin + b * TDIM * NCOL;
    #pragma unroll
    for (int j = 0; j < 2; ++j) {
      const int c = 16 * (ntA + j) + ln;
      #pragma unroll
      for (int r = 0; r < 4; ++r) {
        const int t = 16 * mtA + 4 * q + r;
        yA[j][r] = (t < TDIM && c < NCOL) ? xb[t * NCOL + c] : 0.0f;
      }
    }
  }

  // ---- D2. wave 0: power iteration on G2 (readlane broadcasts, no barriers)
  if (wave == 0) {
    float g2r[36];
    #pragma unroll
    for (int j = 0; j < 36; ++j) g2r[j] = (lane < 36) ? G2[lane * GSTR + j] : 0.0f;
    float v = (lane < 36) ? 1.0f : 0.0f;
    for (int it = 0; it < PITER2; ++it) {
      const int vi = __float_as_int(v);
      float w0 = 0.0f, w1 = 0.0f;
      #pragma unroll
      for (int j = 0; j < 36; j += 2) {
        w0 = fmaf(g2r[j],     __int_as_float(__builtin_amdgcn_readlane(vi, j)),     w0);
        w1 = fmaf(g2r[j + 1], __int_as_float(__builtin_amdgcn_readlane(vi, j + 1)), w1);
      }
      float w = w0 + w1;
      if ((it & 3) == 3) {
        float s = w * w;
        #pragma unroll
        for (int off = 32; off > 0; off >>= 1) s += __shfl_xor(s, off, 64);
        w *= rsqrtf(s);
      }
      v = w;
    }
    // Rayleigh on ORIGINAL G (v unit from it=199 renorm)
    const int vi = __float_as_int(v);
    float w0 = 0.0f, w1 = 0.0f;
    #pragma unroll
    for (int j = 0; j < 36; j += 2) {
      const float gi0 = (lane < 36) ? Gs[lane * GSTR + j]     : 0.0f;
      const float gi1 = (lane < 36) ? Gs[lane * GSTR + j + 1] : 0.0f;
      w0 = fmaf(gi0, __int_as_float(__builtin_amdgcn_readlane(vi, j)),     w0);
      w1 = fmaf(gi1, __int_as_float(__builtin_amdgcn_readlane(vi, j + 1)), w1);
    }
    float num = v * (w0 + w1);
    #pragma unroll
    for (int off = 32; off > 0; off >>= 1) num += __shfl_xor(num, off, 64);
    if (lane == 0) {
      sc[0] = 1.0f / num;        // L_inv
      sc[1] = 0.1f / num;        // thr = lam_f * L_inv
    }
  }
  __syncthreads();

  // ---- E. kill Df alias: zero Y+R regions (y0 = 0, pads = 0)
  {
    unsigned int* z = (unsigned int*)smc;
    for (int i = tid; i < (BY_DTH) / 4; i += 512) z[i] = 0u;
  }
  __syncthreads();
  const float L_inv = sc[0];
  const float thr = sc[1];

  float xR[3][2][4], yR[3][2][4];
  #pragma unroll
  for (int ti = 0; ti < 3; ++ti)
    #pragma unroll
    for (int j = 0; j < 2; ++j)
      #pragma unroll
      for (int r = 0; r < 4; ++r) { xR[ti][j][r] = 0.0f; yR[ti][j][r] = 0.0f; }

  float tk = 1.0f;

  // ---- F. FISTA loop: single-fp16 iterates, D in hi/lo (2 MFMA per operand pair)
  for (int it = 0; it < NITER; ++it) {
    // phase A: R = Y - D y   (M=48, N=64, K=192)
    // hi/lo get SEPARATE accumulators: 4 independent MFMA chains of depth 6
    // (was 2 chains of depth 12) — halves dependent-latency critical path.
    if (wave < 6) {
      floatx4 aH0 = {0.f, 0.f, 0.f, 0.f}, aL0 = {0.f, 0.f, 0.f, 0.f};
      floatx4 aH1 = {0.f, 0.f, 0.f, 0.f}, aL1 = {0.f, 0.f, 0.f, 0.f};
      const int n0 = 16 * ntA + ln, n1 = n0 + 16;
      #pragma unroll
      for (int ks = 0; ks < NKA; ++ks) {
        const int ko = 32 * ks + 8 * q;
        const half8 b0 = *(const half8*)(Yv + n0 * YKS + ko);
        const half8 b1 = *(const half8*)(Yv + n1 * YKS + ko);
        aH0 = __builtin_amdgcn_mfma_f32_16x16x32_f16(DhF[ks], b0, aH0, 0, 0, 0);
        aH1 = __builtin_amdgcn_mfma_f32_16x16x32_f16(DhF[ks], b1, aH1, 0, 0, 0);
        aL0 = __builtin_amdgcn_mfma_f32_16x16x32_f16(DlF[ks], b0, aL0, 0, 0, 0);
        aL1 = __builtin_amdgcn_mfma_f32_16x16x32_f16(DlF[ks], b1, aL1, 0, 0, 0);
      }
      const int t0 = 16 * mtA + 4 * q;
      #pragma unroll
      for (int j = 0; j < 2; ++j) {
        const int c = 16 * (ntA + j) + ln;
        half4 hv;
        #pragma unroll
        for (int r = 0; r < 4; ++r) {
          const float av = j ? (aH1[r] + aL1[r]) : (aH0[r] + aL0[r]);
          hv[r] = (half_t)(yA[j][r] - av);
        }
        *(half4*)(Rv + c * RKS + t0) = hv;
      }
    }
    __syncthreads();

    const float tnew = 0.5f * (1.0f + sqrtf(1.0f + 4.0f * tk * tk));
    const float ttf = (tk - 1.0f) / tnew;
    tk = tnew;

    // phase B: w = y + L_inv D^T R ; shrink + momentum  (M=176, N=64, K=64)
    {
      floatx4 acc[3][2];
      #pragma unroll
      for (int ti = 0; ti < 3; ++ti) {
        acc[ti][0] = (floatx4){0.f, 0.f, 0.f, 0.f};
        acc[ti][1] = (floatx4){0.f, 0.f, 0.f, 0.f};
      }
      const int n1b = nB0 + 16;
      #pragma unroll
      for (int ks = 0; ks < NKB; ++ks) {
        const int ko = 32 * ks + 8 * q;
        const half8 rb0 = *(const half8*)(Rv + nB0 * RKS + ko);
        const half8 rb1 = *(const half8*)(Rv + n1b * RKS + ko);
        #pragma unroll
        for (int ti = 0; ti < 3; ++ti) {
          if (ti < nTB) {
            acc[ti][0] = __builtin_amdgcn_mfma_f32_16x16x32_f16(DtHF[ti][ks], rb0, acc[ti][0], 0, 0, 0);
            acc[ti][0] = __builtin_amdgcn_mfma_f32_16x16x32_f16(DtLF[ti][ks], rb0, acc[ti][0], 0, 0, 0);
            acc[ti][1] = __builtin_amdgcn_mfma_f32_16x16x32_f16(DtHF[ti][ks], rb1, acc[ti][1], 0, 0, 0);
            acc[ti][1] = __builtin_amdgcn_mfma_f32_16x16x32_f16(DtLF[ti][ks], rb1, acc[ti][1], 0, 0, 0);
          }
        }
      }
      #pragma unroll
      for (int ti = 0; ti < 3; ++ti) {
        if (ti < nTB) {
          const int p0 = 16 * (gB + 4 * ti) + 4 * q;
          #pragma unroll
          for (int j = 0; j < 2; ++j) {
            const int c = nB0 + 16 * j;
            half4 hv;
            #pragma unroll
            for (int r = 0; r < 4; ++r) {
              const float w = yR[ti][j][r] + L_inv * acc[ti][j][r];
              const float cl = fminf(fmaxf(w, -thr), thr);   // v_med3 clamp
              const float xn = w - cl;                        // softshrink
              const float yn = xn + ttf * (xn - xR[ti][j][r]);
              xR[ti][j][r] = xn;
              yR[ti][j][r] = yn;
              hv[r] = (half_t)yn;
            }
            *(half4*)(Yv + c * YKS + p0) = hv;
          }
        }
      }
    }
    __syncthreads();
  }

  // ---- G. outputs: C = x_fin
  float* Cb = outC + b * PDIM * NCOL;
  #pragma unroll
  for (int ti = 0; ti < 3; ++ti) {
    if (ti < nTB) {
      #pragma unroll
      for (int j = 0; j < 2; ++j) {
        const int c = nB0 + 16 * j;
        #pragma unroll
        for (int r = 0; r < 4; ++r) {
          const int p = 16 * (gB + 4 * ti) + 4 * q + r;
          if (p < PDIM && c < NCOL) Cb[p * NCOL + c] = xR[ti][j][r];
        }
      }
    }
  }
  // reconst = D @ C : restage x into Y (fp16), rerun phase-A GEMM
  #pragma unroll
  for (int ti = 0; ti < 3; ++ti) {
    if (ti < nTB) {
      const int p0 = 16 * (gB + 4 * ti) + 4 * q;
      #pragma unroll
      for (int j = 0; j < 2; ++j) {
        const int c = nB0 + 16 * j;
        half4 hv;
        #pragma unroll
        for (int r = 0; r < 4; ++r) hv[r] = (half_t)xR[ti][j][r];
        *(half4*)(Yv + c * YKS + p0) = hv;
      }
    }
  }
  __syncthreads();
  if (wave < 6) {
    floatx4 aH0 = {0.f, 0.f, 0.f, 0.f}, aL0 = {0.f, 0.f, 0.f, 0.f};
    floatx4 aH1 = {0.f, 0.f, 0.f, 0.f}, aL1 = {0.f, 0.f, 0.f, 0.f};
    const int n0 = 16 * ntA + ln, n1 = n0 + 16;
    #pragma unroll
    for (int ks = 0; ks < NKA; ++ks) {
      const int ko = 32 * ks + 8 * q;
      const half8 b0 = *(const half8*)(Yv + n0 * YKS + ko);
      const half8 b1 = *(const half8*)(Yv + n1 * YKS + ko);
      aH0 = __builtin_amdgcn_mfma_f32_16x16x32_f16(DhF[ks], b0, aH0, 0, 0, 0);
      aH1 = __builtin_amdgcn_mfma_f32_16x16x32_f16(DhF[ks], b1, aH1, 0, 0, 0);
      aL0 = __builtin_amdgcn_mfma_f32_16x16x32_f16(DlF[ks], b0, aL0, 0, 0, 0);
      aL1 = __builtin_amdgcn_mfma_f32_16x16x32_f16(DlF[ks], b1, aL1, 0, 0, 0);
    }
    float* Rb = outR + b * TDIM * NCOL;
    const int t0 = 16 * mtA + 4 * q;
    #pragma unroll
    for (int j = 0; j < 2; ++j) {
      const int c = 16 * (ntA + j) + ln;
      if (c < NCOL) {
        #pragma unroll
        for (int r = 0; r < 4; ++r) {
          const int t = t0 + r;
          if (t < TDIM) Rb[t * NCOL + c] = (j ? (aH1[r] + aL1[r]) : (aH0[r] + aL0[r]));
        }
      }
    }
  }
}

// ---------------- launch --------------------------------------------------------------

extern "C" void kernel_launch(void* const* d_in, const int* in_sizes, int n_in,
                              void* d_out, int out_size, void* d_ws, size_t ws_size,
                              hipStream_t stream) {
  const float* x     = (const float*)d_in[0];   // (256, 36, 50)
  const float* rho   = (const float*)d_in[1];   // (80,)
  const float* theta = (const float*)d_in[2];   // (80,)

  float* out    = (float*)d_out;
  float* outC   = out;                              // 256*161*50
  float* outDic = out + 256 * PDIM * NCOL;          // 36*161
  float* outR   = outDic + TDIM * PDIM;             // 256*36*50

  hipLaunchKernelGGL(dan_kernel, dim3(256), dim3(512), LDS_TOTAL, stream,
                     x, rho, theta, outC, outDic, outR);
}